// Round 1
// baseline (570.183 us; speedup 1.0000x reference)
//
#include <hip/hip_runtime.h>
#include <hip/hip_bf16.h>

// DenseBlockEnd: out = relu(mask * (node + b1*sum_l A_l@Win_l + b2*BO@Wout))
// B=512, M=256, F=256, L_IN=2, L_OUT=1.
// Fused as C[131072,256] = X[131072,768] @ Wt^T + node, row-masked ReLU.
// Wt (bf16, beta-folded, [n][k] layout) staged in d_ws by prep kernel.

#define BATCH  512
#define MAXA   256
#define FDIM   256
#define KTOT   768
#define ROWS   131072     // BATCH*MAXA
#define TILE_M 128
#define BK     64
#define KPAD   72         // 144B row stride in LDS: 2-way bank aliasing only (free)

typedef __attribute__((ext_vector_type(8))) short  short8;   // 8 bf16 = 4 VGPRs (MFMA A/B frag)
typedef __attribute__((ext_vector_type(4))) float  fx4;      // MFMA C/D frag

__device__ __forceinline__ unsigned short f2bf(float x) {
  // round-to-nearest-even fp32 -> bf16 (inputs are finite normals; NaN not handled)
  unsigned int u = __builtin_bit_cast(unsigned int, x);
  u += 0x7fffu + ((u >> 16) & 1u);
  return (unsigned short)(u >> 16);
}

__device__ __forceinline__ short8 cvt8(fx4 a, fx4 b) {
  short8 r;
  r[0] = (short)f2bf(a[0]); r[1] = (short)f2bf(a[1]);
  r[2] = (short)f2bf(a[2]); r[3] = (short)f2bf(a[3]);
  r[4] = (short)f2bf(b[0]); r[5] = (short)f2bf(b[1]);
  r[6] = (short)f2bf(b[2]); r[7] = (short)f2bf(b[3]);
  return r;
}

// Wt[n*768 + k] = bf16(beta * W[k][n]); k<512 -> W_in (beta1), else W_out (beta2).
// W_in flat: (l*256+f)*256 + o = k*256 + n.
__global__ void prep_weights(const float* __restrict__ Win,
                             const float* __restrict__ Wout,
                             const float* __restrict__ b1,
                             const float* __restrict__ b2,
                             unsigned short* __restrict__ Wt) {
  int id = blockIdx.x * 256 + threadIdx.x;   // 0 .. 196607, id = n*768 + k
  int n = id / KTOT;
  int k = id - n * KTOT;
  float beta, w;
  if (k < 512) { beta = b1[0]; w = Win[k * FDIM + n]; }
  else         { beta = b2[0]; w = Wout[(k - 512) * FDIM + n]; }
  Wt[id] = f2bf(beta * w);
}

__launch_bounds__(512, 4)
__global__ void fused_main(const float* __restrict__ node,
                           const float* __restrict__ acts,   // [2][131072][256]
                           const float* __restrict__ bouts,  // [1][131072][256]
                           const int*   __restrict__ mol_slice,
                           const unsigned short* __restrict__ Wt,
                           float* __restrict__ out) {
  const int tile  = blockIdx.x;        // 1024 tiles of 128 rows
  const int bmol  = tile >> 1;
  const int m0    = (tile & 1) << 7;
  const int slice = mol_slice[bmol];
  const int t     = threadIdx.x;
  const long rowBase = (long)tile * TILE_M;

  if (slice <= m0) {
    // whole tile masked: zero-fill 128x256 output, skip all reads/compute
    fx4 z = {0.f, 0.f, 0.f, 0.f};
    fx4* o4 = (fx4*)(out + rowBase * FDIM);
#pragma unroll
    for (int i = 0; i < 16; ++i) o4[i * 512 + t] = z;
    return;
  }

  __shared__ unsigned short Xs[TILE_M][KPAD];  // 18432 B
  __shared__ unsigned short Ws[FDIM][KPAD];    // 36864 B

  const int lane = t & 63;
  const int wv   = t >> 6;            // 8 waves
  const int wm   = (wv >> 2) << 6;    // wave row offset: 0 / 64
  const int wn   = (wv & 3) << 6;     // wave col offset: 0/64/128/192

  fx4 acc[4][4];
#pragma unroll
  for (int i = 0; i < 4; ++i)
#pragma unroll
    for (int j = 0; j < 4; ++j) acc[i][j] = (fx4){0.f, 0.f, 0.f, 0.f};

  // staging maps: X: 4 threads/row, 16 fp32 each; W: 2 threads/row, 32 bf16 each
  const int xrow = t >> 2;
  const int xc   = (t & 3) << 4;             // fp32 element offset in [0,64)
  const bool xact = (m0 + xrow) < slice;     // masked rows: skip loads (garbage discarded)
  const int wrow = t >> 1;
  const int wc   = (t & 1) << 5;             // bf16 element offset in [0,64)

  for (int kk = 0; kk < KTOT; kk += BK) {
    const float* src = (kk < 256) ? acts : ((kk < 512) ? (acts + 33554432) : bouts);
    const int klocal = kk & 255;

    if (xact) {
      const fx4* g = (const fx4*)(src + (rowBase + xrow) * FDIM + klocal + xc);
      fx4 v0 = g[0], v1 = g[1], v2 = g[2], v3 = g[3];
      *(short8*)&Xs[xrow][xc]     = cvt8(v0, v1);
      *(short8*)&Xs[xrow][xc + 8] = cvt8(v2, v3);
    }
    {
      const int4* g = (const int4*)(Wt + (size_t)wrow * KTOT + kk + wc);
      int4 q0 = g[0], q1 = g[1], q2 = g[2], q3 = g[3];
      *(int4*)&Ws[wrow][wc]      = q0;
      *(int4*)&Ws[wrow][wc + 8]  = q1;
      *(int4*)&Ws[wrow][wc + 16] = q2;
      *(int4*)&Ws[wrow][wc + 24] = q3;
    }
    __syncthreads();

#pragma unroll
    for (int s = 0; s < 2; ++s) {
      const int ko = (s << 5) + ((lane >> 4) << 3);   // k offset for this frag quad
      short8 af[4], bfr[4];
#pragma unroll
      for (int i = 0; i < 4; ++i)
        af[i] = *(const short8*)&Xs[wm + (i << 4) + (lane & 15)][ko];
#pragma unroll
      for (int j = 0; j < 4; ++j)
        bfr[j] = *(const short8*)&Ws[wn + (j << 4) + (lane & 15)][ko];
#pragma unroll
      for (int i = 0; i < 4; ++i)
#pragma unroll
        for (int j = 0; j < 4; ++j)
          acc[i][j] = __builtin_amdgcn_mfma_f32_16x16x32_bf16(af[i], bfr[j], acc[i][j], 0, 0, 0);
    }
    __syncthreads();
  }

  // epilogue: C/D layout col=lane&15, row=(lane>>4)*4+reg (m89-verified)
  const int cq = lane >> 4;
  const int cl = lane & 15;
#pragma unroll
  for (int i = 0; i < 4; ++i) {
    const int rb = wm + (i << 4) + (cq << 2);
#pragma unroll
    for (int r = 0; r < 4; ++r) {
      const int lrow = rb + r;
      const int m = m0 + lrow;
      const long gro = (rowBase + lrow) * FDIM;
      const bool act = m < slice;
#pragma unroll
      for (int j = 0; j < 4; ++j) {
        const int col = wn + (j << 4) + cl;
        float v = 0.f;
        if (act) {
          v = node[gro + col] + acc[i][j][r];
          v = fmaxf(v, 0.f);
        }
        out[gro + col] = v;
      }
    }
  }
}

extern "C" void kernel_launch(void* const* d_in, const int* in_sizes, int n_in,
                              void* d_out, int out_size, void* d_ws, size_t ws_size,
                              hipStream_t stream) {
  const float* node  = (const float*)d_in[0];
  const float* acts  = (const float*)d_in[1];
  const float* bouts = (const float*)d_in[2];
  const int*   mslc  = (const int*)d_in[3];
  const float* Win   = (const float*)d_in[4];
  const float* Wout  = (const float*)d_in[5];
  const float* b1    = (const float*)d_in[6];
  const float* b2    = (const float*)d_in[7];
  float* out = (float*)d_out;
  unsigned short* Wt = (unsigned short*)d_ws;   // 768*256*2 = 393216 B

  prep_weights<<<dim3(768), dim3(256), 0, stream>>>(Win, Wout, b1, b2, Wt);
  fused_main<<<dim3(1024), dim3(512), 0, stream>>>(node, acts, bouts, mslc, Wt, out);
}